// Round 6
// baseline (184.356 us; speedup 1.0000x reference)
//
#include <hip/hip_runtime.h>

// JointBilateralFilter B=16,C=1,H=768,W=1024 fp32, 9x9, sigma_s=2, sigma_r=0.1.
// valid = (sparse != 1.0); constant pad 1.0 => out-of-image taps never contribute.
// ~5% valid density.
//
// Ledger: R9 gather-scan 84.2us. R10 loads-first (+15% instr) -> 96us: VALU-
// issue/exec bound. R11 LDS ds_add_f32 scatter -> 1002us: DS atomic wall, dead.
// R12 4-tile amortize -> 83.0us neutral: fixed cost was NOT the wall; entry
// loop is ~75% of time. VALUBusy-measured cycles ~2x static model => suspected
// codegen bloat: v_pk_*_f32 needs 64b reg-pair operands so splat(sgpr) forces
// hidden v_mov pairs per entry.
//
// R13 (this round): FUSED ASM ENTRY-PAIR. Per while-iteration, decode TWO
// entries branchlessly (missing B redirected to a sentinel table row via SALU
// cselect: SW=600 -> rows 1..8, all -1e30 => w=0, harmless) and compute both
// chains in ONE 24-instruction asm block: scalar VALU with SGPR srcs consumed
// directly (no splats, no pk pairing movs), A/B interleaved to hide v_exp
// latency. ds_read2 + readlane + SALU control stay in C.

#define HH 768
#define WW 1024
#define BB 16
#define CS (-0.18033688011112042f)   /* -log2(e)/8  */
#define CR (-72.13475204444817f)     /* -50*log2(e) */

#define TS 68                        /* table row stride: 2-way-per-half banks (free) */
#define TROWS 31                     /* dy in [-15,15] */
#define TSIZE (TROWS * TS)           /* 2108 floats = 8432 B */
#define TF4   (TSIZE / 4)            /* 527 float4 */
#define SENT_SW 600                  /* sentinel redirect: rows 1..8 all -1e30 */

typedef float f2 __attribute__((ext_vector_type(2)));

__device__ __forceinline__ int rfl(int x) { return __builtin_amdgcn_readfirstlane(x); }
__device__ __forceinline__ float rlanef(float v, int b) {
    return __int_as_float(__builtin_amdgcn_readlane(__float_as_int(v), b));
}

__global__ __launch_bounds__(256) void jbf_kernel(
    const float* __restrict__ sparse,
    const float* __restrict__ depth,
    float* __restrict__ out)
{
    __shared__ __align__(16) float Tab[TSIZE];
    const int tid  = (int)threadIdx.x;
    const int lane = tid & 63;
    const int wv   = tid >> 6;                    // 4 waves/block, 2x2 tiles

    // ---- table build (once per block, shared by all 4 tiles) ----
    {
        float4 s; s.x = -1e30f; s.y = -1e30f; s.z = -1e30f; s.w = -1e30f;
        float4* t4 = (float4*)Tab;
        #pragma unroll
        for (int i = 0; i < 3; ++i) {
            const int idx = tid + 256 * i;
            if (idx < TF4) t4[idx] = s;
        }
    }
    __syncthreads();
    if (tid < 81) {
        const int rr = (tid * 57) >> 9;           // tid/9 for tid<81
        const int cc = tid - 9 * rr;
        const float dy = (float)(rr - 4), dx = (float)(cc - 4);
        Tab[(rr + 11) * TS + cc + 19] = CS * fmaf(dy, dy, dx * dx);
    }
    __syncthreads();

    // ---- hoisted wave-uniform constants ----
    const int ty  = rfl(((int)blockIdx.y << 4) + ((wv >> 1) << 3));  // 8-tall tile
    const int py0 = rfl(min(max(ty - 4, 0), HH - 16));               // 16-row window
    const int tyoff = ty - py0;                   // 0..8
    const int sbrow = TS * (15 - tyoff);          // row part of sbase0

    const size_t plane = (size_t)blockIdx.z * (size_t)(HH * WW);
    const float* sp = sparse + plane;
    const float* dp = depth  + plane;

    const int r  = lane >> 2;                     // 0..15 window row
    const int c0 = (lane & 3) << 1;               // float2 col 0,2,4,6 (+8 per j)
    const int my = lane >> 3, mx = lane & 7;
    const int gy = ty + my;
    const int clane_w = my * TS + mx;             // per-lane table float offset
    const float CRF = CR;                         // -> SGPR for asm "s" operand

    // block covers 128 px in x: 4 tiles of 32 (2 waves each 16 wide)
    const int txb = rfl((int)blockIdx.x * 128 + ((wv & 1) << 4));

// ---- staging: assign into pre-declared register set ----
#define STAGE(TX, PX0, S0, S1, S2, D0, D1, D2, M0, M1)                    \
    const int PX0 = rfl(min(max((TX) - 4, 0), WW - 24));                  \
    {                                                                      \
        const float* wbs = sp + (size_t)(py0 + r) * WW + PX0 + c0;        \
        const float* wbd = dp + (size_t)(py0 + r) * WW + PX0 + c0;        \
        S0 = *(const f2*)(wbs);                                            \
        S1 = *(const f2*)(wbs + 8);                                        \
        S2 = *(const f2*)(wbs + 16);                                       \
        D0 = *(const f2*)(wbd);                                            \
        D1 = *(const f2*)(wbd + 8);                                        \
        D2 = *(const f2*)(wbd + 16);                                       \
        M0 = dp[(size_t)gy * WW + (TX) + mx];                              \
        M1 = dp[(size_t)gy * WW + (TX) + mx + 8];                          \
    }

// ---- process one 16x8 wave tile; entry math in fused asm ----
#define PROCESS(TX, PX0, S0, S1, S2, D0, D1, D2, M0, M1)                  \
    {                                                                      \
        const int txoff = (TX) - PX0;             /* 0..8 */               \
        const int sbase0 = sbrow + (23 - txoff) - 8;                       \
        const float nx = -(M0), ny = -(M1);                                \
        float dnA0 = 0.f, dnA1 = 0.f, dnB0 = 0.f, dnB1 = 0.f;              \
        float nmA0 = 0.f, nmA1 = 0.f, nmB0 = 0.f, nmB1 = 0.f;              \
        _Pragma("unroll")                                                  \
        for (int j = 0; j < 3; ++j) {                                      \
            const f2 s2 = (j == 0) ? S0 : (j == 1) ? S1 : S2;              \
            const f2 d2 = (j == 0) ? D0 : (j == 1) ? D1 : D2;              \
            _Pragma("unroll")                                              \
            for (int k = 0; k < 2; ++k) {                                  \
                const float svk = k ? s2.y : s2.x;                         \
                const float dvk = k ? d2.y : d2.x;                         \
                const int sbase = sbase0 + 8 * j + k;      /* SALU */      \
                unsigned long long m = __ballot(svk != 1.0f);              \
                while (m) {                                /* uniform */   \
                    const int b0 = (int)__builtin_ctzll(m);                \
                    m &= (m - 1ull);                                       \
                    const int SW0 = sbase + (b0 >> 2) * TS                 \
                                    + ((b0 & 3) << 1);     /* SALU */      \
                    const bool hasB = (m != 0ull);                         \
                    const int b1r = (int)__builtin_ctzll(                  \
                        m | 0x8000000000000000ull);                        \
                    const int b1 = hasB ? b1r : 0;                         \
                    const int SW1 = hasB ? (sbase + (b1r >> 2) * TS        \
                                    + ((b1r & 3) << 1)) : SENT_SW;         \
                    m &= (m - 1ull);                       /* 0 stays 0 */ \
                    const float* tb0 = Tab + (SW0 - clane_w);              \
                    const float* tb1 = Tab + (SW1 - clane_w);              \
                    const float tpA0 = tb0[8], tpA1 = tb0[0];              \
                    const float tpB0 = tb1[8], tpB1 = tb1[0];              \
                    const float svA = rlanef(svk, b0);                     \
                    const float dvA = rlanef(dvk, b0);                     \
                    const float svB = rlanef(svk, b1);                     \
                    const float dvB = rlanef(dvk, b1);                     \
                    float t0, t1, t2, t3, a0, a1, a2, a3;                  \
                    asm("v_add_f32 %[t0], %[dvA], %[nx]\n\t"               \
                        "v_add_f32 %[t1], %[dvA], %[ny]\n\t"               \
                        "v_add_f32 %[t2], %[dvB], %[nx]\n\t"               \
                        "v_add_f32 %[t3], %[dvB], %[ny]\n\t"               \
                        "v_mul_f32 %[t0], %[t0], %[t0]\n\t"                \
                        "v_mul_f32 %[t1], %[t1], %[t1]\n\t"                \
                        "v_mul_f32 %[t2], %[t2], %[t2]\n\t"                \
                        "v_mul_f32 %[t3], %[t3], %[t3]\n\t"                \
                        "v_fma_f32 %[a0], %[t0], %[cr], %[pA0]\n\t"        \
                        "v_fma_f32 %[a1], %[t1], %[cr], %[pA1]\n\t"        \
                        "v_fma_f32 %[a2], %[t2], %[cr], %[pB0]\n\t"        \
                        "v_fma_f32 %[a3], %[t3], %[cr], %[pB1]\n\t"        \
                        "v_exp_f32 %[a0], %[a0]\n\t"                       \
                        "v_exp_f32 %[a1], %[a1]\n\t"                       \
                        "v_exp_f32 %[a2], %[a2]\n\t"                       \
                        "v_exp_f32 %[a3], %[a3]\n\t"                       \
                        "v_add_f32 %[dA0], %[dA0], %[a0]\n\t"              \
                        "v_add_f32 %[dA1], %[dA1], %[a1]\n\t"              \
                        "v_add_f32 %[dB0], %[dB0], %[a2]\n\t"              \
                        "v_add_f32 %[dB1], %[dB1], %[a3]\n\t"              \
                        "v_fmac_f32 %[nA0], %[svA], %[a0]\n\t"             \
                        "v_fmac_f32 %[nA1], %[svA], %[a1]\n\t"             \
                        "v_fmac_f32 %[nB0], %[svB], %[a2]\n\t"             \
                        "v_fmac_f32 %[nB1], %[svB], %[a3]"                 \
                        : [t0] "=&v"(t0), [t1] "=&v"(t1),                  \
                          [t2] "=&v"(t2), [t3] "=&v"(t3),                  \
                          [a0] "=&v"(a0), [a1] "=&v"(a1),                  \
                          [a2] "=&v"(a2), [a3] "=&v"(a3),                  \
                          [dA0] "+v"(dnA0), [dA1] "+v"(dnA1),              \
                          [dB0] "+v"(dnB0), [dB1] "+v"(dnB1),              \
                          [nA0] "+v"(nmA0), [nA1] "+v"(nmA1),              \
                          [nB0] "+v"(nmB0), [nB1] "+v"(nmB1)               \
                        : [dvA] "s"(dvA), [svA] "s"(svA),                  \
                          [dvB] "s"(dvB), [svB] "s"(svB),                  \
                          [cr] "s"(CRF),                                   \
                          [nx] "v"(nx), [ny] "v"(ny),                      \
                          [pA0] "v"(tpA0), [pA1] "v"(tpA1),                \
                          [pB0] "v"(tpB0), [pB1] "v"(tpB1));               \
                }                                                          \
            }                                                              \
        }                                                                  \
        const float n0 = nmA0 + nmB0, n1 = nmA1 + nmB1;                    \
        const float e0 = dnA0 + dnB0, e1 = dnA1 + dnB1;                    \
        float r0 = n0 * __builtin_amdgcn_rcpf(e0 + 1e-8f);                 \
        r0 = (e0 < 1e-8f) ? 1.0f : r0;                                     \
        float r1 = n1 * __builtin_amdgcn_rcpf(e1 + 1e-8f);                 \
        r1 = (e1 < 1e-8f) ? 1.0f : r1;                                     \
        float* op = out + plane + (size_t)gy * WW + (TX) + mx;             \
        op[0] = r0;                                                        \
        op[8] = r1;                                                        \
    }

    // ---- two register sets, 1-ahead software pipeline over 4 tiles ----
    f2 sA0, sA1, sA2, dA0, dA1, dA2; float mA0, mA1;
    f2 sB0, sB1, sB2, dB0, dB1, dB2; float mB0, mB1;

    const int tx0 = txb;
    const int tx1 = txb + 32;
    const int tx2 = txb + 64;
    const int tx3 = txb + 96;

    STAGE(tx0, px0a, sA0, sA1, sA2, dA0, dA1, dA2, mA0, mA1)
    STAGE(tx1, px0b, sB0, sB1, sB2, dB0, dB1, dB2, mB0, mB1)
    PROCESS(tx0, px0a, sA0, sA1, sA2, dA0, dA1, dA2, mA0, mA1)
    STAGE(tx2, px0c, sA0, sA1, sA2, dA0, dA1, dA2, mA0, mA1)
    PROCESS(tx1, px0b, sB0, sB1, sB2, dB0, dB1, dB2, mB0, mB1)
    STAGE(tx3, px0d, sB0, sB1, sB2, dB0, dB1, dB2, mB0, mB1)
    PROCESS(tx2, px0c, sA0, sA1, sA2, dA0, dA1, dA2, mA0, mA1)
    PROCESS(tx3, px0d, sB0, sB1, sB2, dB0, dB1, dB2, mB0, mB1)

#undef STAGE
#undef PROCESS
}

extern "C" void kernel_launch(void* const* d_in, const int* in_sizes, int n_in,
                              void* d_out, int out_size, void* d_ws, size_t ws_size,
                              hipStream_t stream)
{
    const float* sparse = (const float*)d_in[0];
    const float* depth  = (const float*)d_in[1];
    float* out = (float*)d_out;
    dim3 grid(WW / 128, HH / 16, BB);   // 8 x 48 x 16 blocks, 4 waves, 4 tiles/block
    jbf_kernel<<<grid, dim3(256, 1, 1), 0, stream>>>(sparse, depth, out);
}

// Round 7
// 175.160 us; speedup vs baseline: 1.0525x; 1.0525x over previous
//
#include <hip/hip_runtime.h>

// JointBilateralFilter B=16,C=1,H=768,W=1024 fp32, 9x9, sigma_s=2, sigma_r=0.1.
// valid = (sparse != 1.0); constant pad 1.0 => out-of-image taps never contribute.
// ~5% valid density.
//
// Ledger: R9 gather-scan 84.2. R10 loads-first (+15% instr) -> 96: in-loop
// instr-proportional. R11 LDS-atomic scatter -> 1002: DS wall, dead. R12
// 4-tile amortize+prefetch -> 83.0 neutral. R13 fused-asm entry pair -> 96:
// phantom-B math +16% entries => +16% time; asm reverted. LAW: t ~ in-loop
// instr x ~2-3x issue rate. Static issue content ~25us; we pay 83.
//
// R14 (this round): FORCE STAGED VALUES INTO REGISTERS. VGPR_Count=32 proves
// the 26-reg staged set never lived in regs -- compiler sank the staging loads
// into the loop, putting a ~200-400cy L2 load at each of the 6 ballot heads
// (the mystery 2-3x; also why R12's prefetch was cosmetic: loads sunk anyway,
// and FETCH halved with no time change = L2 re-reads). Fix: at PROCESS entry,
// unpack staged f2 -> scalars and pin with empty asm volatile "+v" operands.
// Pin sits after the NEXT tile's prefetch issues => latency hidden under the
// previous tile's loop. Math/control identical to R12.

#define HH 768
#define WW 1024
#define BB 16
#define CS (-0.18033688011112042f)   /* -log2(e)/8  */
#define CR (-72.13475204444817f)     /* -50*log2(e) */

#define TS 68                        /* table row stride: 2-way-per-half banks (free) */
#define TROWS 31                     /* dy in [-15,15] */
#define TSIZE (TROWS * TS)           /* 2108 floats = 8432 B */
#define TF4   (TSIZE / 4)            /* 527 float4 */

typedef float f2 __attribute__((ext_vector_type(2)));

__device__ __forceinline__ int rfl(int x) { return __builtin_amdgcn_readfirstlane(x); }
__device__ __forceinline__ float rlanef(float v, int b) {
    return __int_as_float(__builtin_amdgcn_readlane(__float_as_int(v), b));
}
__device__ __forceinline__ f2 splat(float x) { f2 r; r.x = x; r.y = x; return r; }

__global__ __launch_bounds__(256) void jbf_kernel(
    const float* __restrict__ sparse,
    const float* __restrict__ depth,
    float* __restrict__ out)
{
    __shared__ __align__(16) float Tab[TSIZE];
    const int tid  = (int)threadIdx.x;
    const int lane = tid & 63;
    const int wv   = tid >> 6;                    // 4 waves/block, 2x2 tiles

    // ---- table build (once per block, shared by all 4 tiles) ----
    {
        float4 s; s.x = -1e30f; s.y = -1e30f; s.z = -1e30f; s.w = -1e30f;
        float4* t4 = (float4*)Tab;
        #pragma unroll
        for (int i = 0; i < 3; ++i) {
            const int idx = tid + 256 * i;
            if (idx < TF4) t4[idx] = s;
        }
    }
    __syncthreads();
    if (tid < 81) {
        const int rr = (tid * 57) >> 9;           // tid/9 for tid<81
        const int cc = tid - 9 * rr;
        const float dy = (float)(rr - 4), dx = (float)(cc - 4);
        Tab[(rr + 11) * TS + cc + 19] = CS * fmaf(dy, dy, dx * dx);
    }
    __syncthreads();

    // ---- hoisted wave-uniform constants ----
    const int ty  = rfl(((int)blockIdx.y << 4) + ((wv >> 1) << 3));  // 8-tall tile
    const int py0 = rfl(min(max(ty - 4, 0), HH - 16));               // 16-row window
    const int tyoff = ty - py0;                   // 0..8
    const int sbrow = TS * (15 - tyoff);          // row part of sbase0

    const size_t plane = (size_t)blockIdx.z * (size_t)(HH * WW);
    const float* sp = sparse + plane;
    const float* dp = depth  + plane;

    const int r  = lane >> 2;                     // 0..15 window row
    const int c0 = (lane & 3) << 1;               // float2 col 0,2,4,6 (+8 per j)
    const int my = lane >> 3, mx = lane & 7;
    const int gy = ty + my;
    const int clane_w = my * TS + mx;             // per-lane table float offset
    const f2 crp = splat(CR);

    // block covers 128 px in x: 4 tiles of 32 (2 waves each 16 wide)
    const int txb = rfl((int)blockIdx.x * 128 + ((wv & 1) << 4));

// ---- staging: issue loads into pre-declared register set ----
#define STAGE(TX, PX0, S0, S1, S2, D0, D1, D2, M0, M1)                    \
    const int PX0 = rfl(min(max((TX) - 4, 0), WW - 24));                  \
    {                                                                      \
        const float* wbs = sp + (size_t)(py0 + r) * WW + PX0 + c0;        \
        const float* wbd = dp + (size_t)(py0 + r) * WW + PX0 + c0;        \
        S0 = *(const f2*)(wbs);                                            \
        S1 = *(const f2*)(wbs + 8);                                        \
        S2 = *(const f2*)(wbs + 16);                                       \
        D0 = *(const f2*)(wbd);                                            \
        D1 = *(const f2*)(wbd + 8);                                        \
        D2 = *(const f2*)(wbd + 16);                                       \
        M0 = dp[(size_t)gy * WW + (TX) + mx];                              \
        M1 = dp[(size_t)gy * WW + (TX) + mx + 8];                          \
    }

// ---- process one 16x8 wave tile (R9 packed math) with pinned registers ----
#define PROCESS(TX, PX0, S0, S1, S2, D0, D1, D2, M0, M1)                  \
    {                                                                      \
        /* unpack to scalars and PIN: forces all staged values resident */ \
        float x00 = S0.x, x01 = S0.y, x10 = S1.x, x11 = S1.y;              \
        float x20 = S2.x, x21 = S2.y;                                      \
        float y00 = D0.x, y01 = D0.y, y10 = D1.x, y11 = D1.y;              \
        float y20 = D2.x, y21 = D2.y;                                      \
        float nx = -(M0), ny = -(M1);                                      \
        asm volatile("" : "+v"(x00), "+v"(x01), "+v"(x10), "+v"(x11),      \
                          "+v"(x20), "+v"(x21), "+v"(y00), "+v"(y01),      \
                          "+v"(y10), "+v"(y11), "+v"(y20), "+v"(y21),      \
                          "+v"(nx), "+v"(ny));                             \
        const int txoff = (TX) - PX0;             /* 0..8 */               \
        const int sbase0 = sbrow + (23 - txoff) - 8;                       \
        f2 nmyd; nmyd.x = nx; nmyd.y = ny;                                 \
        f2 numA = splat(0.0f), denA = splat(0.0f);                         \
        f2 numB = splat(0.0f), denB = splat(0.0f);                         \
        _Pragma("unroll")                                                  \
        for (int j = 0; j < 3; ++j) {                                      \
            _Pragma("unroll")                                              \
            for (int k = 0; k < 2; ++k) {                                  \
                const float svk = (j == 0) ? (k ? x01 : x00)               \
                                : (j == 1) ? (k ? x11 : x10)               \
                                           : (k ? x21 : x20);              \
                const float dvk = (j == 0) ? (k ? y01 : y00)               \
                                : (j == 1) ? (k ? y11 : y10)               \
                                           : (k ? y21 : y20);              \
                const int sbase = sbase0 + 8 * j + k;      /* SALU */      \
                unsigned long long m = __ballot(svk != 1.0f);              \
                while (m) {                                /* uniform */   \
                    const int b0 = (int)__builtin_ctzll(m);                \
                    m &= (m - 1ull);                                       \
                    {                                                      \
                        const float sv_e = rlanef(svk, b0);                \
                        const float dv_e = rlanef(dvk, b0);                \
                        const int SW = sbase + (b0 >> 2) * TS              \
                                       + ((b0 & 3) << 1);  /* SALU */      \
                        const float* tb = Tab + (SW - clane_w);            \
                        f2 tp; tp.x = tb[8]; tp.y = tb[0]; /* ds_read2 */  \
                        const f2 diff = nmyd + splat(dv_e);                \
                        const f2 q = diff * crp;                           \
                        const f2 arg = q * diff + tp;      /* pk_fma */    \
                        f2 w; w.x = __builtin_amdgcn_exp2f(arg.x);         \
                        w.y = __builtin_amdgcn_exp2f(arg.y);               \
                        denA += w;                                         \
                        numA += w * splat(sv_e);           /* pk_fma */    \
                    }                                                      \
                    if (m) {                               /* B chain */   \
                        const int b1 = (int)__builtin_ctzll(m);            \
                        m &= (m - 1ull);                                   \
                        const float sv_e = rlanef(svk, b1);                \
                        const float dv_e = rlanef(dvk, b1);                \
                        const int SW = sbase + (b1 >> 2) * TS              \
                                       + ((b1 & 3) << 1);                  \
                        const float* tb = Tab + (SW - clane_w);            \
                        f2 tp; tp.x = tb[8]; tp.y = tb[0];                 \
                        const f2 diff = nmyd + splat(dv_e);                \
                        const f2 q = diff * crp;                           \
                        const f2 arg = q * diff + tp;                      \
                        f2 w; w.x = __builtin_amdgcn_exp2f(arg.x);         \
                        w.y = __builtin_amdgcn_exp2f(arg.y);               \
                        denB += w;                                         \
                        numB += w * splat(sv_e);                           \
                    }                                                      \
                }                                                          \
            }                                                              \
        }                                                                  \
        const float n0 = numA.x + numB.x, n1 = numA.y + numB.y;            \
        const float e0 = denA.x + denB.x, e1 = denA.y + denB.y;            \
        float r0 = n0 * __builtin_amdgcn_rcpf(e0 + 1e-8f);                 \
        r0 = (e0 < 1e-8f) ? 1.0f : r0;                                     \
        float r1 = n1 * __builtin_amdgcn_rcpf(e1 + 1e-8f);                 \
        r1 = (e1 < 1e-8f) ? 1.0f : r1;                                     \
        float* op = out + plane + (size_t)gy * WW + (TX) + mx;             \
        op[0] = r0;                                                        \
        op[8] = r1;                                                        \
    }

    // ---- two register sets, 1-ahead software pipeline over 4 tiles ----
    f2 sA0, sA1, sA2, dA0, dA1, dA2; float mA0, mA1;
    f2 sB0, sB1, sB2, dB0, dB1, dB2; float mB0, mB1;

    const int tx0 = txb;
    const int tx1 = txb + 32;
    const int tx2 = txb + 64;
    const int tx3 = txb + 96;

    STAGE(tx0, px0a, sA0, sA1, sA2, dA0, dA1, dA2, mA0, mA1)
    STAGE(tx1, px0b, sB0, sB1, sB2, dB0, dB1, dB2, mB0, mB1)
    PROCESS(tx0, px0a, sA0, sA1, sA2, dA0, dA1, dA2, mA0, mA1)
    STAGE(tx2, px0c, sA0, sA1, sA2, dA0, dA1, dA2, mA0, mA1)
    PROCESS(tx1, px0b, sB0, sB1, sB2, dB0, dB1, dB2, mB0, mB1)
    STAGE(tx3, px0d, sB0, sB1, sB2, dB0, dB1, dB2, mB0, mB1)
    PROCESS(tx2, px0c, sA0, sA1, sA2, dA0, dA1, dA2, mA0, mA1)
    PROCESS(tx3, px0d, sB0, sB1, sB2, dB0, dB1, dB2, mB0, mB1)

#undef STAGE
#undef PROCESS
}

extern "C" void kernel_launch(void* const* d_in, const int* in_sizes, int n_in,
                              void* d_out, int out_size, void* d_ws, size_t ws_size,
                              hipStream_t stream)
{
    const float* sparse = (const float*)d_in[0];
    const float* depth  = (const float*)d_in[1];
    float* out = (float*)d_out;
    dim3 grid(WW / 128, HH / 16, BB);   // 8 x 48 x 16 blocks, 4 waves, 4 tiles/block
    jbf_kernel<<<grid, dim3(256, 1, 1), 0, stream>>>(sparse, depth, out);
}

// Round 8
// 175.038 us; speedup vs baseline: 1.0532x; 1.0007x over previous
//
#include <hip/hip_runtime.h>

// JointBilateralFilter B=16,C=1,H=768,W=1024 fp32, 9x9, sigma_s=2, sigma_r=0.1.
// valid = (sparse != 1.0); constant pad 1.0 => out-of-image taps never contribute.
// ~5% valid density.
//
// Ledger: R9 gather-scan 84.2. R10 loads-first (+15% instr) -> 96. R11 LDS-
// atomic scatter -> 1002 (DS atomic wall, dead). R12 4-tile amortize -> 83.0.
// R13 fused-asm pair -> 96 (phantom-B entries). R14 register pin -> neutral,
// VGPR stuck at 32 (compiler sinks loads legally). LAW: t ~ in-loop issue
// count; entry math is ~24cy but we pay ~84cy/entry => the serial loop's
// scalarization machinery (2x readlane VALU->SGPR, ctz/mask SALU, ballots) is
// the cost, not the math.
//
// R15 (this round): LDS ENTRY COMPACTION. Extraction is serial (readlane per
// entry) but compaction is data-parallel: each valid lane writes its OWN
// {sv, dv, table_byte_base} to a per-wave LDS queue at position
// base + mbcnt(mask) -- no readlane, 6 predicated ds_write_b128 per tile.
// Entry loop: broadcast ds_read_b128 (uniform addr = free), v_add, ds_read2
// table, 7-op packed math => ~12 issues/entry vs ~40. Unroll x2 with a w=0
// sentinel pad entry (table row of -1e30s) -- no tail branch. CAP=128
// entries/tile; overflow (never at 5%) falls back to old readlane loop.
// LDS 16752 B => still 8 blocks/CU (threads-bound).

#define HH 768
#define WW 1024
#define BB 16
#define CS (-0.18033688011112042f)   /* -log2(e)/8  */
#define CR (-72.13475204444817f)     /* -50*log2(e) */

#define TS 68                        /* table row stride (floats) */
#define TROWS 31                     /* dy in [-15,15] */
#define TSIZE (TROWS * TS)           /* 2108 floats = 8432 B */
#define TF4   (TSIZE / 4)            /* 527 float4 */
#define CAP   128                    /* entry queue capacity per wave-tile */
#define SENT_B 2400                  /* sentinel table byte offset: rows 1..8 all -1e30 */
/* LDS: table + 4 waves x (CAP+2) float4 entries */
#define LDSF (TSIZE + 4 * (CAP + 2) * 4)

typedef float f2 __attribute__((ext_vector_type(2)));

__device__ __forceinline__ int rfl(int x) { return __builtin_amdgcn_readfirstlane(x); }
__device__ __forceinline__ float rlanef(float v, int b) {
    return __int_as_float(__builtin_amdgcn_readlane(__float_as_int(v), b));
}
__device__ __forceinline__ f2 splat(float x) { f2 r; r.x = x; r.y = x; return r; }

__global__ __launch_bounds__(256) void jbf_kernel(
    const float* __restrict__ sparse,
    const float* __restrict__ depth,
    float* __restrict__ out)
{
    __shared__ __align__(16) float Lds[LDSF];
    float* Tab = Lds;
    const int tid  = (int)threadIdx.x;
    const int lane = tid & 63;
    const int wv   = tid >> 6;                    // 4 waves/block, 2x2 tiles
    float4* ebuf = (float4*)(Lds + TSIZE) + wv * (CAP + 2);

    // ---- table build (once per block, shared by all 4 tiles) ----
    {
        float4 s; s.x = -1e30f; s.y = -1e30f; s.z = -1e30f; s.w = -1e30f;
        float4* t4 = (float4*)Tab;
        #pragma unroll
        for (int i = 0; i < 3; ++i) {
            const int idx = tid + 256 * i;
            if (idx < TF4) t4[idx] = s;
        }
    }
    __syncthreads();
    if (tid < 81) {
        const int rr = (tid * 57) >> 9;           // tid/9 for tid<81
        const int cc = tid - 9 * rr;
        const float dy = (float)(rr - 4), dx = (float)(cc - 4);
        Tab[(rr + 11) * TS + cc + 19] = CS * fmaf(dy, dy, dx * dx);
    }
    __syncthreads();

    // ---- hoisted wave-uniform constants ----
    const int ty  = rfl(((int)blockIdx.y << 4) + ((wv >> 1) << 3));  // 8-tall tile
    const int py0 = rfl(min(max(ty - 4, 0), HH - 16));               // 16-row window
    const int tyoff = ty - py0;                   // 0..8
    const int sbrow = TS * (15 - tyoff);          // row part of sbase0

    const size_t plane = (size_t)blockIdx.z * (size_t)(HH * WW);
    const float* sp = sparse + plane;
    const float* dp = depth  + plane;

    const int r  = lane >> 2;                     // 0..15 window row
    const int c0 = (lane & 3) << 1;               // float2 col 0,2,4,6 (+8 per j)
    const int my = lane >> 3, mx = lane & 7;
    const int gy = ty + my;
    const int clane_w = my * TS + mx;             // reader per-lane table offset
    const int lwr = (lane >> 2) * TS + ((lane & 3) << 1);  // writer per-lane SW part
    const f2 crp = splat(CR);

    // block covers 128 px in x: 4 tiles of 32 (2 waves each 16 wide)
    const int txb = rfl((int)blockIdx.x * 128 + ((wv & 1) << 4));

// ---- staging: issue loads into pre-declared register set ----
#define STAGE(TX, PX0, S0, S1, S2, D0, D1, D2, M0, M1)                    \
    const int PX0 = rfl(min(max((TX) - 4, 0), WW - 24));                  \
    {                                                                      \
        const float* wbs = sp + (size_t)(py0 + r) * WW + PX0 + c0;        \
        const float* wbd = dp + (size_t)(py0 + r) * WW + PX0 + c0;        \
        S0 = *(const f2*)(wbs);                                            \
        S1 = *(const f2*)(wbs + 8);                                        \
        S2 = *(const f2*)(wbs + 16);                                       \
        D0 = *(const f2*)(wbd);                                            \
        D1 = *(const f2*)(wbd + 8);                                        \
        D2 = *(const f2*)(wbd + 16);                                       \
        M0 = dp[(size_t)gy * WW + (TX) + mx];                              \
        M1 = dp[(size_t)gy * WW + (TX) + mx + 8];                          \
    }

// ---- process one 16x8 wave tile via compaction + broadcast entry loop ----
#define PROCESS(TX, PX0, S0, S1, S2, D0, D1, D2, M0, M1)                  \
    {                                                                      \
        const int txoff = (TX) - PX0;             /* 0..8 */               \
        const int sb0 = sbrow + (23 - txoff) - 8;  /* SGPR */              \
        f2 nmyd; nmyd.x = -(M0); nmyd.y = -(M1);                           \
        f2 numA = splat(0.0f), denA = splat(0.0f);                         \
        f2 numB = splat(0.0f), denB = splat(0.0f);                         \
        int base = 0;                                                      \
        _Pragma("unroll")                                                  \
        for (int j = 0; j < 3; ++j) {                                      \
            const f2 s2 = (j == 0) ? S0 : (j == 1) ? S1 : S2;              \
            const f2 d2 = (j == 0) ? D0 : (j == 1) ? D1 : D2;              \
            _Pragma("unroll")                                              \
            for (int k = 0; k < 2; ++k) {                                  \
                const float svk = k ? s2.y : s2.x;                         \
                const float dvk = k ? d2.y : d2.x;                         \
                const bool p = (svk != 1.0f);                              \
                unsigned long long m = __ballot(p);                        \
                const int swb = (sb0 + 8 * j + k + lwr) << 2;              \
                const int pre = (int)__builtin_amdgcn_mbcnt_hi(            \
                    (unsigned)(m >> 32),                                   \
                    __builtin_amdgcn_mbcnt_lo((unsigned)m, 0u));           \
                const int wpos = base + pre;                               \
                if (p && wpos < CAP) {                                     \
                    float4 e; e.x = svk; e.y = dvk;                        \
                    e.z = __int_as_float(swb); e.w = 0.f;                  \
                    ebuf[wpos] = e;                                        \
                }                                                          \
                unsigned long long of = __ballot(p && wpos >= CAP);        \
                base += __builtin_popcountll(m);                           \
                while (of) {                       /* ~never taken */      \
                    const int b0 = (int)__builtin_ctzll(of);               \
                    of &= (of - 1ull);                                     \
                    const float sv_e = rlanef(svk, b0);                    \
                    const float dv_e = rlanef(dvk, b0);                    \
                    const int SW = (sb0 + 8 * j + k) + (b0 >> 2) * TS      \
                                   + ((b0 & 3) << 1);                      \
                    const float* tb = Tab + (SW - clane_w);                \
                    f2 tp; tp.x = tb[8]; tp.y = tb[0];                     \
                    const f2 diff = nmyd + splat(dv_e);                    \
                    const f2 q = diff * crp;                               \
                    const f2 arg = q * diff + tp;                          \
                    f2 w; w.x = __builtin_amdgcn_exp2f(arg.x);             \
                    w.y = __builtin_amdgcn_exp2f(arg.y);                   \
                    denA += w;                                             \
                    numA += w * splat(sv_e);                               \
                }                                                          \
            }                                                              \
        }                                                                  \
        const int n = min(base, CAP);                                      \
        if (lane < 2) {                            /* sentinel pad: w=0 */ \
            float4 e; e.x = 1.0f; e.y = 0.f;                               \
            e.z = __int_as_float(SENT_B); e.w = 0.f;                       \
            ebuf[n + lane] = e;                                            \
        }                                                                  \
        for (int i = 0; i < n; i += 2) {           /* uniform, no tail */  \
            const float4 e0 = ebuf[i];             /* broadcast b128 */    \
            const float4 e1 = ebuf[i + 1];                                 \
            const float* tb0 = (const float*)((const char*)Tab             \
                               + __float_as_int(e0.z)) - clane_w;          \
            const float* tb1 = (const float*)((const char*)Tab             \
                               + __float_as_int(e1.z)) - clane_w;          \
            f2 tp0; tp0.x = tb0[8]; tp0.y = tb0[0];                        \
            f2 tp1; tp1.x = tb1[8]; tp1.y = tb1[0];                        \
            {                                                              \
                const f2 diff = nmyd + splat(e0.y);                        \
                const f2 q = diff * crp;                                   \
                const f2 arg = q * diff + tp0;                             \
                f2 w; w.x = __builtin_amdgcn_exp2f(arg.x);                 \
                w.y = __builtin_amdgcn_exp2f(arg.y);                       \
                denA += w;                                                 \
                numA += w * splat(e0.x);                                   \
            }                                                              \
            {                                                              \
                const f2 diff = nmyd + splat(e1.y);                        \
                const f2 q = diff * crp;                                   \
                const f2 arg = q * diff + tp1;                             \
                f2 w; w.x = __builtin_amdgcn_exp2f(arg.x);                 \
                w.y = __builtin_amdgcn_exp2f(arg.y);                       \
                denB += w;                                                 \
                numB += w * splat(e1.x);                                   \
            }                                                              \
        }                                                                  \
        const float n0 = numA.x + numB.x, n1 = numA.y + numB.y;            \
        const float e0s = denA.x + denB.x, e1s = denA.y + denB.y;          \
        float r0 = n0 * __builtin_amdgcn_rcpf(e0s + 1e-8f);                \
        r0 = (e0s < 1e-8f) ? 1.0f : r0;                                    \
        float r1 = n1 * __builtin_amdgcn_rcpf(e1s + 1e-8f);                \
        r1 = (e1s < 1e-8f) ? 1.0f : r1;                                    \
        float* op = out + plane + (size_t)gy * WW + (TX) + mx;             \
        op[0] = r0;                                                        \
        op[8] = r1;                                                        \
    }

    // ---- two register sets, 1-ahead software pipeline over 4 tiles ----
    f2 sA0, sA1, sA2, dA0, dA1, dA2; float mA0, mA1;
    f2 sB0, sB1, sB2, dB0, dB1, dB2; float mB0, mB1;

    const int tx0 = txb;
    const int tx1 = txb + 32;
    const int tx2 = txb + 64;
    const int tx3 = txb + 96;

    STAGE(tx0, px0a, sA0, sA1, sA2, dA0, dA1, dA2, mA0, mA1)
    STAGE(tx1, px0b, sB0, sB1, sB2, dB0, dB1, dB2, mB0, mB1)
    PROCESS(tx0, px0a, sA0, sA1, sA2, dA0, dA1, dA2, mA0, mA1)
    STAGE(tx2, px0c, sA0, sA1, sA2, dA0, dA1, dA2, mA0, mA1)
    PROCESS(tx1, px0b, sB0, sB1, sB2, dB0, dB1, dB2, mB0, mB1)
    STAGE(tx3, px0d, sB0, sB1, sB2, dB0, dB1, dB2, mB0, mB1)
    PROCESS(tx2, px0c, sA0, sA1, sA2, dA0, dA1, dA2, mA0, mA1)
    PROCESS(tx3, px0d, sB0, sB1, sB2, dB0, dB1, dB2, mB0, mB1)

#undef STAGE
#undef PROCESS
}

extern "C" void kernel_launch(void* const* d_in, const int* in_sizes, int n_in,
                              void* d_out, int out_size, void* d_ws, size_t ws_size,
                              hipStream_t stream)
{
    const float* sparse = (const float*)d_in[0];
    const float* depth  = (const float*)d_in[1];
    float* out = (float*)d_out;
    dim3 grid(WW / 128, HH / 16, BB);   // 8 x 48 x 16 blocks, 4 waves, 4 tiles/block
    jbf_kernel<<<grid, dim3(256, 1, 1), 0, stream>>>(sparse, depth, out);
}

// Round 11
// 173.313 us; speedup vs baseline: 1.0637x; 1.0100x over previous
//
#include <hip/hip_runtime.h>

// JointBilateralFilter B=16,C=1,H=768,W=1024 fp32, 9x9, sigma_s=2, sigma_r=0.1.
// valid = (sparse != 1.0); constant pad 1.0 => out-of-image taps never contribute.
// ~5% valid density.
//
// Ledger: R9 gather-scan(16x8,P=2) 84.2. R10 loads-first -> 96 (instr-prop).
// R11 LDS-atomic scatter -> 1002 (dead). R12 4-tile amortize -> 83.0 (frame
// kept; fixed cost NOT the wall). R13 fused-asm pair -> 96 (phantom entries).
// R14 pin -> neutral. R15 LDS compaction -> 87 (readlane machinery not the
// wall). R16/R17 forced v_pk_* asm -> absmax 1.4e7 FAIL (hand VOP3P op_sel_hi
// defaults differ from compiler; packed-math line abandoned).
//
// R18 (this round): SHRINK BROADCAST WASTE. cost/px = rho*(T+8)(S+8)*[F/(64P)
// + M/64]. R7 picked 16x8/P=2 (window/tile=3.0) assuming F dominates; R12
// disproved that. Math-dominant optimum is 8x8/P=1: window/tile = 256/64 =
// 2.0 => 33% less per-entry math broadcast. All-scalar fp32 math (packed
// question moot), float4 staging (1 pair/lane), single ds_read_b32 per entry,
// TS=40 (== 8 mod 32): clane=my*40+mx hits each bank once per 32-lane half =>
// ZERO LDS conflicts. Same ballot/ctz/readlane machinery, same -1e30 sentinel
// table, same R12 A/B-pipelined 4-tile frame.

#define HH 768
#define WW 1024
#define BB 16
#define CS (-0.18033688011112042f)   /* -log2(e)/8  */
#define CR (-72.13475204444817f)     /* -50*log2(e) */

#define TS 40                        /* table row stride: 40 mod 32 = 8 => conflict-free */
#define TROWS 31                     /* dy in [-15,15] */
#define TSIZE (TROWS * TS)           /* 1240 floats = 4960 B */
#define TF4   (TSIZE / 4)            /* 310 float4 */

__device__ __forceinline__ int rfl(int x) { return __builtin_amdgcn_readfirstlane(x); }
__device__ __forceinline__ float rlanef(float v, int b) {
    return __int_as_float(__builtin_amdgcn_readlane(__float_as_int(v), b));
}

__global__ __launch_bounds__(256) void jbf_kernel(
    const float* __restrict__ sparse,
    const float* __restrict__ depth,
    float* __restrict__ out)
{
    __shared__ __align__(16) float Tab[TSIZE];
    const int tid  = (int)threadIdx.x;
    const int lane = tid & 63;
    const int wv   = tid >> 6;                    // 4 waves/block (2x2 of 8x8)

    // ---- table build (once per block): fill -1e30, write 81 in-box cells ----
    {
        float4 s; s.x = -1e30f; s.y = -1e30f; s.z = -1e30f; s.w = -1e30f;
        float4* t4 = (float4*)Tab;
        #pragma unroll
        for (int i = 0; i < 2; ++i) {
            const int idx = tid + 256 * i;
            if (idx < TF4) t4[idx] = s;
        }
    }
    __syncthreads();
    if (tid < 81) {
        const int rr = (tid * 57) >> 9;           // tid/9 for tid<81
        const int cc = tid - 9 * rr;
        const float dy = (float)(rr - 4), dx = (float)(cc - 4);
        Tab[(rr + 11) * TS + cc + 11] = CS * fmaf(dy, dy, dx * dx);
    }
    __syncthreads();

    // ---- wave/lane geometry ----
    const int wr = wv >> 1, wc = wv & 1;          // wave position in 2x2
    const int my = lane >> 3, mx = lane & 7;      // 8x8 tile coords
    const int sr = lane >> 2, sc = (lane & 3) << 2; // 16x16 window stager

    const int ty  = rfl(((int)blockIdx.y << 4) + (wr << 3));   // 8-tall tile
    const int py0 = rfl(min(max(ty - 4, 0), HH - 16));         // 16-row window
    const int tyoff = ty - py0;                   // 0..8
    const int gy = ty + my;

    const size_t plane = (size_t)blockIdx.z * (size_t)(HH * WW);
    const float* sp = sparse + plane;
    const float* dp = depth  + plane;

    const int clane = my * TS + mx;               // per-lane table offset (bank-perfect)
    const float crf = CR;

    // block covers 64 px in x: 4 steps of 16 (2 waves each 8 wide)
    const int txb = rfl((int)blockIdx.x * 64 + (wc << 3));

// ---- staging: one float4 pair + center depth per lane ----
#define STAGE(TX, PX0, S4, D4, MD)                                        \
    const int PX0 = rfl(min(max((TX) - 4, 0), WW - 16));                  \
    {                                                                      \
        const size_t wb = (size_t)(py0 + sr) * WW + PX0 + sc;             \
        S4 = *(const float4*)(sp + wb);                                    \
        D4 = *(const float4*)(dp + wb);                                    \
        MD = dp[(size_t)gy * WW + (TX) + mx];                              \
    }

// ---- process one 8x8 wave tile: 4 ballots, A/B dual-chain scalar math ----
#define PROCESS(TX, PX0, S4, D4, MD)                                      \
    {                                                                      \
        const int txoff = (TX) - PX0;             /* 0..8 */               \
        const int sbase0 = TS * (15 - tyoff) + (15 - txoff);               \
        const float md = (MD);                                             \
        float numA = 0.f, denA = 0.f, numB = 0.f, denB = 0.f;              \
        _Pragma("unroll")                                                  \
        for (int k = 0; k < 4; ++k) {                                      \
            const float svk = (k == 0) ? S4.x : (k == 1) ? S4.y            \
                            : (k == 2) ? S4.z : S4.w;                      \
            const float dvk = (k == 0) ? D4.x : (k == 1) ? D4.y            \
                            : (k == 2) ? D4.z : D4.w;                      \
            const int sbk = sbase0 + k;                /* SALU */          \
            unsigned long long m = __ballot(svk != 1.0f);                  \
            while (m) {                                /* uniform */       \
                const int b0 = (int)__builtin_ctzll(m);                    \
                m &= (m - 1ull);                                           \
                {                                                          \
                    const float sv0 = rlanef(svk, b0);                     \
                    const float dv0 = rlanef(dvk, b0);                     \
                    const int SW = sbk + (b0 >> 2) * TS                    \
                                   + ((b0 & 3) << 2);  /* SALU */          \
                    const float tp = Tab[SW - clane];  /* ds_read_b32 */   \
                    const float diff = dv0 - md;                           \
                    const float arg = fmaf(diff * crf, diff, tp);          \
                    const float w = __builtin_amdgcn_exp2f(arg);           \
                    denA += w;                                             \
                    numA = fmaf(sv0, w, numA);                             \
                }                                                          \
                if (m) {                               /* B chain */       \
                    const int b1 = (int)__builtin_ctzll(m);                \
                    m &= (m - 1ull);                                       \
                    const float sv1 = rlanef(svk, b1);                     \
                    const float dv1 = rlanef(dvk, b1);                     \
                    const int SW = sbk + (b1 >> 2) * TS                    \
                                   + ((b1 & 3) << 2);                      \
                    const float tp = Tab[SW - clane];                      \
                    const float diff = dv1 - md;                           \
                    const float arg = fmaf(diff * crf, diff, tp);          \
                    const float w = __builtin_amdgcn_exp2f(arg);           \
                    denB += w;                                             \
                    numB = fmaf(sv1, w, numB);                             \
                }                                                          \
            }                                                              \
        }                                                                  \
        const float n = numA + numB;                                       \
        const float e = denA + denB;                                       \
        float rr2 = n * __builtin_amdgcn_rcpf(e + 1e-8f);                  \
        rr2 = (e < 1e-8f) ? 1.0f : rr2;                                    \
        out[plane + (size_t)gy * WW + (TX) + mx] = rr2;                    \
    }

    // ---- two register sets, 1-ahead software pipeline over 4 tiles ----
    float4 s4A, d4A; float mdA;
    float4 s4B, d4B; float mdB;

    const int tx0 = txb;
    const int tx1 = txb + 16;
    const int tx2 = txb + 32;
    const int tx3 = txb + 48;

    STAGE(tx0, px0a, s4A, d4A, mdA)
    STAGE(tx1, px0b, s4B, d4B, mdB)
    PROCESS(tx0, px0a, s4A, d4A, mdA)
    STAGE(tx2, px0c, s4A, d4A, mdA)
    PROCESS(tx1, px0b, s4B, d4B, mdB)
    STAGE(tx3, px0d, s4B, d4B, mdB)
    PROCESS(tx2, px0c, s4A, d4A, mdA)
    PROCESS(tx3, px0d, s4B, d4B, mdB)

#undef STAGE
#undef PROCESS
}

extern "C" void kernel_launch(void* const* d_in, const int* in_sizes, int n_in,
                              void* d_out, int out_size, void* d_ws, size_t ws_size,
                              hipStream_t stream)
{
    const float* sparse = (const float*)d_in[0];
    const float* depth  = (const float*)d_in[1];
    float* out = (float*)d_out;
    dim3 grid(WW / 64, HH / 16, BB);   // 16 x 48 x 16 blocks, 4 waves, 4 tiles/block
    jbf_kernel<<<grid, dim3(256, 1, 1), 0, stream>>>(sparse, depth, out);
}